// Round 1
// 1147.166 us; speedup vs baseline: 1.1205x; 1.1205x over previous
//
#include <hip/hip_runtime.h>

// ---------- types ----------
typedef __attribute__((ext_vector_type(4))) float f32x4;
typedef __attribute__((ext_vector_type(8))) short s16x8;
typedef __attribute__((ext_vector_type(4))) short s16x4;
typedef __attribute__((ext_vector_type(8))) _Float16 f16x8;
typedef __attribute__((ext_vector_type(4))) _Float16 f16x4;

// ---------- problem dims (fixed) ----------
constexpr int DB   = 2;
constexpr int DS   = 2048;
constexpr int DHID = 1024;
constexpr int DNH  = 16;
constexpr int DHD  = 64;
constexpr int GM = DB * DS;   // 4096 rows for all projections
constexpr int GN = DHID;      // 1024
constexpr int GK = DHID;      // 1024

// ---------- bf16 / fp16 helpers ----------
__device__ __forceinline__ unsigned short f2bf_bits(float x) {
  unsigned int u = __float_as_uint(x);
  u += 0x7fffu + ((u >> 16) & 1u);
  return (unsigned short)(u >> 16);
}
__device__ __forceinline__ float bf2f(unsigned short b) {
  return __uint_as_float(((unsigned int)b) << 16);
}
__device__ __forceinline__ void split2(float x, unsigned short &h, unsigned short &l) {
  unsigned short hb = f2bf_bits(x);
  h = hb;
  l = f2bf_bits(x - bf2f(hb));
}
__device__ __forceinline__ unsigned short f2h_bits(float x) {
  _Float16 h = (_Float16)x;
  unsigned short u;
  __builtin_memcpy(&u, &h, 2);
  return u;
}

// =====================================================================
// one-shot fp32 -> bf16 hi/lo conversion (removes per-tile split2 from GEMMs)
// =====================================================================
__global__ __launch_bounds__(256) void conv_hilo(
    const float* __restrict__ x, unsigned short* __restrict__ hi,
    unsigned short* __restrict__ lo, int n4)
{
  int i = blockIdx.x * 256 + threadIdx.x;
  if (i >= n4) return;
  f32x4 v = ((const f32x4*)x)[i];
  s16x4 h, l;
#pragma unroll
  for (int e = 0; e < 4; e++) {
    unsigned short hh, ll;
    split2(v[e], hh, ll);
    h[e] = (short)hh; l[e] = (short)ll;
  }
  ((s16x4*)hi)[i] = h;
  ((s16x4*)lo)[i] = l;
}

__global__ __launch_bounds__(256) void conv_hi(
    const float* __restrict__ x, unsigned short* __restrict__ hi, int n4)
{
  int i = blockIdx.x * 256 + threadIdx.x;
  if (i >= n4) return;
  f32x4 v = ((const f32x4*)x)[i];
  s16x4 h;
#pragma unroll
  for (int e = 0; e < 4; e++) h[e] = (short)f2bf_bits(v[e]);
  ((s16x4*)hi)[i] = h;
}

// =====================================================================
// GEMM: C[m][n] = sum_k A[m][k] * W[n][k] + bias[n]  (pre-converted bf16 in)
// MODE 0: hi/lo A and W (3-term MFMA), store bf16 hi+lo   (Q, K proj)
// MODE 1: single bf16, store fp16                         (V proj)
// MODE 2: single bf16, store fp32                         (output proj)
// tile 64x64, BK=32, 256 threads (4 waves, each 32x32); grid 1024 -> 4 blk/CU
// =====================================================================
template<int MODE>
__global__ __launch_bounds__(256, 4) void gemm_x(
    const unsigned short* __restrict__ Ahi, const unsigned short* __restrict__ Alo,
    const unsigned short* __restrict__ Whi, const unsigned short* __restrict__ Wlo,
    const float* __restrict__ bias,
    unsigned short* __restrict__ o_hi, unsigned short* __restrict__ o_lo,
    float* __restrict__ o_f)
{
  constexpr int BK  = 32;
  constexpr int LDA = BK + 8;   // frag reads land 2-way max (free)
  __shared__ __attribute__((aligned(16))) unsigned short Ah[64][LDA];
  __shared__ __attribute__((aligned(16))) unsigned short Bh[64][LDA];
  __shared__ __attribute__((aligned(16))) unsigned short Al[(MODE == 0) ? 64 : 1][LDA];
  __shared__ __attribute__((aligned(16))) unsigned short Bl[(MODE == 0) ? 64 : 1][LDA];

  const int t    = threadIdx.x;
  const int lane = t & 63;
  const int wave = t >> 6;
  const int quad = lane >> 4;
  const int l16  = lane & 15;
  const int m0 = blockIdx.y * 64;
  const int n0 = blockIdx.x * 64;
  const int wr = (wave >> 1) * 32;
  const int wc = (wave & 1) * 32;
  const int sr = t >> 2;        // 0..63
  const int sc = (t & 3) * 8;   // 0,8,16,24

  f32x4 acc[2][2];
#pragma unroll
  for (int i = 0; i < 2; i++)
#pragma unroll
    for (int j = 0; j < 2; j++) acc[i][j] = (f32x4){0.f, 0.f, 0.f, 0.f};

  for (int k0 = 0; k0 < GK; k0 += BK) {
    const size_t ga = (size_t)(m0 + sr) * GK + k0 + sc;
    const size_t gb = (size_t)(n0 + sr) * GK + k0 + sc;
    *(s16x8*)&Ah[sr][sc] = *(const s16x8*)(Ahi + ga);
    *(s16x8*)&Bh[sr][sc] = *(const s16x8*)(Whi + gb);
    if constexpr (MODE == 0) {
      *(s16x8*)&Al[sr][sc] = *(const s16x8*)(Alo + ga);
      *(s16x8*)&Bl[sr][sc] = *(const s16x8*)(Wlo + gb);
    }
    __syncthreads();

    s16x8 af[2], bf[2], afl[2], bfl[2];
#pragma unroll
    for (int i = 0; i < 2; i++) {
      af[i] = *(const s16x8*)&Ah[wr + i * 16 + l16][quad * 8];
      bf[i] = *(const s16x8*)&Bh[wc + i * 16 + l16][quad * 8];
      if constexpr (MODE == 0) {
        afl[i] = *(const s16x8*)&Al[wr + i * 16 + l16][quad * 8];
        bfl[i] = *(const s16x8*)&Bl[wc + i * 16 + l16][quad * 8];
      }
    }
#pragma unroll
    for (int i = 0; i < 2; i++)
#pragma unroll
      for (int j = 0; j < 2; j++) {
        acc[i][j] = __builtin_amdgcn_mfma_f32_16x16x32_bf16(af[i], bf[j], acc[i][j], 0, 0, 0);
        if constexpr (MODE == 0) {
          acc[i][j] = __builtin_amdgcn_mfma_f32_16x16x32_bf16(af[i],  bfl[j], acc[i][j], 0, 0, 0);
          acc[i][j] = __builtin_amdgcn_mfma_f32_16x16x32_bf16(afl[i], bf[j],  acc[i][j], 0, 0, 0);
        }
      }
    __syncthreads();
  }

  // ---- epilogue: C/D layout col=lane&15, row=quad*4+reg ----
#pragma unroll
  for (int j = 0; j < 2; j++) {
    int n = n0 + wc + j * 16 + l16;
    float bj = bias[n];
#pragma unroll
    for (int i = 0; i < 2; i++) {
      int mbase = m0 + wr + i * 16 + quad * 4;
#pragma unroll
      for (int r = 0; r < 4; r++) {
        float v = acc[i][j][r] + bj;
        size_t off = (size_t)(mbase + r) * GN + n;
        if constexpr (MODE == 0) {
          unsigned short hb, lb; split2(v, hb, lb);
          o_hi[off] = hb; o_lo[off] = lb;
        } else if constexpr (MODE == 1) {
          o_hi[off] = f2h_bits(v);
        } else {
          o_f[off] = v;
        }
      }
    }
  }
}

// =====================================================================
// V (B,S,HID) fp16 -> Vt (B,NH,HD,S) fp16 so PV B-fragments are contiguous
// =====================================================================
__global__ __launch_bounds__(256) void transpose_v(
    const unsigned short* __restrict__ V, unsigned short* __restrict__ Vt)
{
  __shared__ unsigned short tile[64][72];
  const int t   = threadIdx.x;
  const int blk = blockIdx.x;           // B*NH*(S/64) = 1024
  const int st  = blk & 31;
  const int bh  = blk >> 5;             // 0..31
  const int b = bh >> 4, h = bh & 15;

  const int sr = t >> 3, d8 = (t & 7) * 8;
#pragma unroll
  for (int i = 0; i < 2; i++) {
    int s = sr + i * 32;
    s16x8 v = *(const s16x8*)&V[((size_t)(b * DS + st * 64 + s)) * DHID + h * DHD + d8];
#pragma unroll
    for (int j = 0; j < 8; j++) tile[d8 + j][s] = (unsigned short)v[j];
  }
  __syncthreads();
  const int dr = t >> 3, s8 = (t & 7) * 8;
#pragma unroll
  for (int i = 0; i < 2; i++) {
    int d = dr + i * 32;
    s16x8 u = *(const s16x8*)&tile[d][s8];
    *(s16x8*)&Vt[((size_t)bh * DHD + d) * DS + st * 64 + s8] = u;
  }
}

// =====================================================================
// Fused attention: one WG per (b, h, 16 q-rows). 512 threads (8 waves).
// Constant-shift softmax (exp(s-4)): identical after normalization, lets
// phase 1 fuse QK^T + exp and store unnormalized P as fp16 in LDS.
// LDS = 70.5 KB -> 2 WG/CU (vs 135 KB / 1 WG before).
//  phase 1: scores = split-bf16 QK^T * 0.125 + beta*ss, mask, exp -> P fp16;
//           row sums reduced in registers (shfl) + tiny LDS cross-wave
//  phase 2: rinv per row; wout = P * rinv (nontemporal f32x4 stores)
//  phase 3: PV in fp16 MFMA, split-K across wave pairs, scale by rinv
// =====================================================================
constexpr int PPAD = 2056;  // fp16 row stride (2048 + 8): balanced banks

__global__ __launch_bounds__(512, 4) void attn_kernel(
    const unsigned short* __restrict__ Qhi, const unsigned short* __restrict__ Qlo,
    const unsigned short* __restrict__ Khi, const unsigned short* __restrict__ Klo,
    const unsigned short* __restrict__ Vt,
    const float* __restrict__ ssim, const int* __restrict__ amask,
    const float* __restrict__ betap,
    float* __restrict__ wout, unsigned short* __restrict__ obf)
{
  extern __shared__ char smraw[];
  float* partial = (float*)smraw;        // 4 * 256
  float* wsum    = partial + 1024;       // 8 waves * 16 rows
  float* stats   = wsum + 128;           // 16
  unsigned short* P = (unsigned short*)(stats + 16);  // 16 x PPAD fp16

  const int t    = threadIdx.x;
  const int lane = t & 63;
  const int wave = t >> 6;
  const int quad = lane >> 4;
  const int l16  = lane & 15;

  const int blk = blockIdx.x;            // 4096
  const int qt = blk & 127;
  const int h  = (blk >> 7) & 15;
  const int b  = blk >> 11;
  const int q0 = qt * 16;
  const size_t qkvBase = (size_t)b * DS * DHID + h * DHD;
  const float beta = *betap;

  // ---- Q fragments (A-operand: m=lane&15, k=quad*8+j), hi & lo, 2 k-steps ----
  s16x8 qh[2], ql[2];
  {
    size_t ro = qkvBase + (size_t)(q0 + l16) * DHID + quad * 8;
    qh[0] = *(const s16x8*)(Qhi + ro);
    ql[0] = *(const s16x8*)(Qlo + ro);
    qh[1] = *(const s16x8*)(Qhi + ro + 32);
    ql[1] = *(const s16x8*)(Qlo + ro + 32);
  }

  // ---- phase 1: scores -> exp(s-4) -> P (fp16), row-sum in regs ----
  float ps[4] = {0.f, 0.f, 0.f, 0.f};
  for (int i = 0; i < 16; i++) {
    int kc0 = (wave + 8 * i) * 16;       // 8 waves x 16 = 128 n-blocks
    size_t ko = qkvBase + (size_t)(kc0 + l16) * DHID + quad * 8;
    s16x8 kh0 = *(const s16x8*)(Khi + ko);
    s16x8 kl0 = *(const s16x8*)(Klo + ko);
    s16x8 kh1 = *(const s16x8*)(Khi + ko + 32);
    s16x8 kl1 = *(const s16x8*)(Klo + ko + 32);
    f32x4 a  = (f32x4){0.f, 0.f, 0.f, 0.f};
    f32x4 a2 = (f32x4){0.f, 0.f, 0.f, 0.f};
    a  = __builtin_amdgcn_mfma_f32_16x16x32_bf16(qh[0], kh0, a,  0, 0, 0);
    a2 = __builtin_amdgcn_mfma_f32_16x16x32_bf16(qh[1], kh1, a2, 0, 0, 0);
    a  = __builtin_amdgcn_mfma_f32_16x16x32_bf16(qh[0], kl0, a,  0, 0, 0);
    a2 = __builtin_amdgcn_mfma_f32_16x16x32_bf16(qh[1], kl1, a2, 0, 0, 0);
    a  = __builtin_amdgcn_mfma_f32_16x16x32_bf16(ql[0], kh0, a,  0, 0, 0);
    a2 = __builtin_amdgcn_mfma_f32_16x16x32_bf16(ql[1], kh1, a2, 0, 0, 0);

    int kcol = kc0 + l16;
    int mk = amask[b * DS + kcol];
    const float* ssp = ssim + ((size_t)b * DS + q0 + quad * 4) * DS + kcol;
#pragma unroll
    for (int r = 0; r < 4; r++) {
      float s = (a[r] + a2[r]) * 0.125f + beta * ssp[(size_t)r * DS];
      float ev = mk ? __expf(s - 4.0f) : 0.0f;   // constant shift: exact softmax
      ps[r] += ev;
      P[(quad * 4 + r) * PPAD + kcol] = f2h_bits(ev);
    }
  }
  // reduce row sums across the 16 lanes of each quad-group
#pragma unroll
  for (int o = 1; o < 16; o <<= 1) {
#pragma unroll
    for (int r = 0; r < 4; r++) ps[r] += __shfl_xor(ps[r], o);
  }
  if (l16 == 0) {
#pragma unroll
    for (int r = 0; r < 4; r++) wsum[wave * 16 + quad * 4 + r] = ps[r];
  }
  __syncthreads();

  if (t < 16) {
    float ssum = 0.f;
#pragma unroll
    for (int w = 0; w < 8; w++) ssum += wsum[w * 16 + t];
    stats[t] = 1.0f / ssum;
  }
  __syncthreads();

  // ---- phase 2: normalize + write weights (nontemporal, coalesced) ----
  {
    int r = t >> 5, l32 = t & 31;
    float rinv = stats[r];
    size_t wbase = (((size_t)b * DNH + h) * DS + q0 + r) * DS;
    const unsigned short* Pr = P + r * PPAD;
#pragma unroll
    for (int i = 0; i < 16; i++) {
      int col = l32 * 4 + i * 128;
      f16x4 hv = *(const f16x4*)(Pr + col);
      f32x4 v;
      v[0] = (float)hv[0] * rinv; v[1] = (float)hv[1] * rinv;
      v[2] = (float)hv[2] * rinv; v[3] = (float)hv[3] * rinv;
      __builtin_nontemporal_store(v, (f32x4*)(wout + wbase + col));
    }
  }

  // ---- phase 3: PV fp16. wave: n-block = wave&3 (16 d cols), k-half = wave>>2 ----
  const int nbd = wave & 3;
  const int khf = wave >> 2;
  f32x4 acc0 = (f32x4){0.f, 0.f, 0.f, 0.f};
  f32x4 acc1 = (f32x4){0.f, 0.f, 0.f, 0.f};
  {
    const _Float16* Vh = (const _Float16*)Vt;
    size_t vbase = (((size_t)b * DNH + h) * DHD + nbd * 16 + l16) * DS + khf * 1024;
    const unsigned short* Pm = P + l16 * PPAD + khf * 1024;
    for (int ks = 0; ks < 32; ks += 2) {
      int k0 = ks * 32 + quad * 8;
      int k1 = k0 + 32;
      f16x8 pa0 = *(const f16x8*)(Pm + k0);
      f16x8 vb0 = *(const f16x8*)(Vh + vbase + k0);
      f16x8 pa1 = *(const f16x8*)(Pm + k1);
      f16x8 vb1 = *(const f16x8*)(Vh + vbase + k1);
      acc0 = __builtin_amdgcn_mfma_f32_16x16x32_f16(pa0, vb0, acc0, 0, 0, 0);
      acc1 = __builtin_amdgcn_mfma_f32_16x16x32_f16(pa1, vb1, acc1, 0, 0, 0);
    }
  }
  f32x4 acc = acc0 + acc1;
  if (wave >= 4) {
#pragma unroll
    for (int r = 0; r < 4; r++)
      partial[nbd * 256 + (quad * 4 + r) * 16 + l16] = acc[r];
  }
  __syncthreads();
  if (wave < 4) {
#pragma unroll
    for (int r = 0; r < 4; r++) {
      int qr = quad * 4 + r;
      float v = (acc[r] + partial[nbd * 256 + qr * 16 + l16]) * stats[qr];
      obf[((size_t)b * DS + q0 + qr) * DHID + h * DHD + nbd * 16 + l16] = f2bf_bits(v);
    }
  }
}

// =====================================================================
// launch
// =====================================================================
extern "C" void kernel_launch(void* const* d_in, const int* in_sizes, int n_in,
                              void* d_out, int out_size, void* d_ws, size_t ws_size,
                              hipStream_t stream) {
  (void)in_sizes; (void)n_in; (void)out_size; (void)ws_size;
  const float* qin  = (const float*)d_in[0];
  const float* kin  = (const float*)d_in[1];
  const float* vin  = (const float*)d_in[2];
  const int*   amask = (const int*)d_in[3];
  const float* ssim = (const float*)d_in[4];
  const float* Wq = (const float*)d_in[5];
  const float* bq = (const float*)d_in[6];
  const float* Wk = (const float*)d_in[7];
  const float* bk = (const float*)d_in[8];
  const float* Wv = (const float*)d_in[9];
  const float* bv = (const float*)d_in[10];
  const float* Wo = (const float*)d_in[11];
  const float* bo = (const float*)d_in[12];
  const float* beta = (const float*)d_in[13];

  // workspace carve: 7.5 x 8MB planes = 60 MB (aliased; <= proven 64 MB)
  constexpr size_t NE = (size_t)GM * GK;   // 4096*1024
  unsigned short* wsu = (unsigned short*)d_ws;
  unsigned short* Qhi = wsu + 0 * NE;
  unsigned short* Qlo = wsu + 1 * NE;
  unsigned short* Khi = wsu + 2 * NE;
  unsigned short* Klo = wsu + 3 * NE;
  unsigned short* Vt  = wsu + 4 * NE;
  unsigned short* cAh = wsu + 5 * NE;   // conv A-hi scratch; later Obf (attn out)
  unsigned short* cAl = wsu + 6 * NE;   // conv A-lo scratch; later Vh (V fp16)
  unsigned short* cWh = wsu + 7 * NE;   // conv W-hi (NE/4 elements)
  unsigned short* cWl = cWh + NE / 4;   // conv W-lo (NE/4 elements)

  float* outp = (float*)d_out;                 // (B,S,HID) fp32
  float* wout = outp + (size_t)DB * DS * DHID; // (B,NH,S,S) fp32

  const int nA4 = (int)(NE / 4);        // 1M  float4s per activation tensor
  const int nW4 = (int)(NE / 16);       // 256K float4s per weight matrix
  dim3 gg(GN / 64, GM / 64);            // (16, 64) = 1024 blocks -> 4/CU

  // Q projection
  conv_hilo<<<nA4 / 256, 256, 0, stream>>>(qin, cAh, cAl, nA4);
  conv_hilo<<<nW4 / 256, 256, 0, stream>>>(Wq, cWh, cWl, nW4);
  gemm_x<0><<<gg, 256, 0, stream>>>(cAh, cAl, cWh, cWl, bq, Qhi, Qlo, nullptr);
  // K projection
  conv_hilo<<<nA4 / 256, 256, 0, stream>>>(kin, cAh, cAl, nA4);
  conv_hilo<<<nW4 / 256, 256, 0, stream>>>(Wk, cWh, cWl, nW4);
  gemm_x<0><<<gg, 256, 0, stream>>>(cAh, cAl, cWh, cWl, bk, Khi, Klo, nullptr);
  // V projection (fp16 out) + transpose
  conv_hi<<<nA4 / 256, 256, 0, stream>>>(vin, cAh, nA4);
  conv_hi<<<nW4 / 256, 256, 0, stream>>>(Wv, cWh, nW4);
  gemm_x<1><<<gg, 256, 0, stream>>>(cAh, nullptr, cWh, nullptr, bv, cAl, nullptr, nullptr);
  transpose_v<<<DB * DNH * (DS / 64), 256, 0, stream>>>(cAl, Vt);

  const int attnLds = (1024 + 128 + 16) * 4 + 16 * PPAD * 2;  // 70464 B -> 2 WG/CU
  attn_kernel<<<DB * DNH * (DS / 16), 512, attnLds, stream>>>(
      Qhi, Qlo, Khi, Klo, Vt, ssim, amask, beta, wout, cAh);

  // output projection (A = attn out bf16, written directly by attn)
  conv_hi<<<nW4 / 256, 256, 0, stream>>>(Wo, cWh, nW4);
  gemm_x<2><<<gg, 256, 0, stream>>>(cAh, nullptr, cWh, nullptr, bo, nullptr, nullptr, outp);
}